// Round 7
// baseline (309.420 us; speedup 1.0000x reference)
//
#include <hip/hip_runtime.h>
#include <cstdint>
#include <cstddef>

#define SEQ 4096
#define DM  2048
#define NH  16
#define KVH 4
#define HD  128
// softmax scale folded into Q at RoPE time: 1/sqrt(128) * log2(e)
#define QSCALE (0.08838834764831845f * 1.4426950408889634f)

typedef short bf16_t;
typedef __attribute__((ext_vector_type(8))) short bf16x8;
typedef __attribute__((ext_vector_type(4))) float f32x4;
typedef __attribute__((ext_vector_type(16))) float f32x16;
typedef __attribute__((ext_vector_type(4))) unsigned uint32x4;

__device__ __forceinline__ bf16_t f2b(float f) {
  unsigned u = __builtin_bit_cast(unsigned, f);
  u += 0x7fffu + ((u >> 16) & 1u);          // RNE
  return (bf16_t)(u >> 16);
}
__device__ __forceinline__ float b2f(bf16_t s) {
  unsigned u = ((unsigned)(unsigned short)s) << 16;
  return __builtin_bit_cast(float, u);
}
// v_cvt_pk_bf16_f32: packs 2 f32 -> 2 bf16 (RNE) in one instr (no builtin; T12)
__device__ __forceinline__ unsigned cvtpk(float lo, float hi) {
  unsigned r;
  asm("v_cvt_pk_bf16_f32 %0, %1, %2" : "=v"(r) : "v"(lo), "v"(hi));
  return r;
}

// async global->LDS, 16B per lane. LDS dest is wave-uniform base + lane*16
// (linear); swizzling is done by permuting the per-lane GLOBAL source.
__device__ __forceinline__ void gload_lds16(const void* gsrc, void* ldst) {
  __builtin_amdgcn_global_load_lds(
      (__attribute__((address_space(1))) void*)gsrc,
      (__attribute__((address_space(3))) void*)ldst, 16, 0, 0);
}

// ---------------- cast x -> bf16 ----------------
__global__ void cast_x_bf16(const float* __restrict__ x, bf16_t* __restrict__ xb, int n4) {
  int i = blockIdx.x * 256 + threadIdx.x;
  if (i >= n4) return;
  float4 v = ((const float4*)x)[i];
  union { bf16_t h[4]; unsigned long long u; } o;
  o.h[0] = f2b(v.x); o.h[1] = f2b(v.y); o.h[2] = f2b(v.z); o.h[3] = f2b(v.w);
  ((unsigned long long*)xb)[i] = o.u;
}

// ---------------- W [K][N] fp32 -> Wt [N][K] bf16 ----------------
__global__ void transpose_cast_w(const float* __restrict__ W, bf16_t* __restrict__ Wt,
                                 int K, int N) {
  __shared__ float tile[32][33];
  int k0 = blockIdx.y * 32, n0 = blockIdx.x * 32;
  int tx = threadIdx.x, ty = threadIdx.y;
#pragma unroll
  for (int dy = 0; dy < 32; dy += 8)
    tile[ty + dy][tx] = W[(size_t)(k0 + ty + dy) * N + n0 + tx];
  __syncthreads();
#pragma unroll
  for (int dy = 0; dy < 32; dy += 8)
    Wt[(size_t)(n0 + ty + dy) * K + k0 + tx] = f2b(tile[tx][ty + dy]);
}

// ---------------- RoPE cos/sin table ----------------
__global__ void rope_tab(float* __restrict__ ct, float* __restrict__ st) {
  int i = blockIdx.x * 256 + threadIdx.x;
  if (i >= SEQ * 64) return;
  int t = i >> 6, j = i & 63;
  float invf = expf(-(float)j * (9.210340371976184f / 64.0f)); // 10000^(-j/64)
  float ang = (float)t * invf;
  ct[i] = cosf(ang);
  st[i] = sinf(ang);
}

// ---------------- in-place RoPE on bf16 Q and K (Q pre-scaled) ----------------
__global__ void rope_apply(bf16_t* __restrict__ Qb, bf16_t* __restrict__ KVb,
                           const float* __restrict__ ct, const float* __restrict__ st) {
  int i = blockIdx.x * 256 + threadIdx.x;
  const int qtot = SEQ * NH * 64;
  const int tot = qtot + SEQ * KVH * 64;
  if (i >= tot) return;
  bf16_t* base; int t, j; float scl;
  if (i < qtot) {
    t = i >> 10; int rem = i & 1023; int hh = rem >> 6; j = rem & 63;
    base = Qb + (size_t)t * DM + hh * HD;
    scl = QSCALE;                              // fold softmax scale + log2e into Q
  } else {
    int i2 = i - qtot;
    t = i2 >> 8; int rem = i2 & 255; int hh = rem >> 6; j = rem & 63;
    base = KVb + (size_t)t * 1024 + hh * HD;   // K half = cols 0..511
    scl = 1.0f;
  }
  float c = ct[t * 64 + j], s = st[t * 64 + j];
  float x0 = b2f(base[j]);
  float x1 = b2f(base[j + 64]);
  base[j]      = f2b((x0 * c - x1 * s) * scl);
  base[j + 64] = f2b((x1 * c + x0 * s) * scl);
}

// ---------------- V half of KVb [T][1024] -> Vt [512][T], key-permuted ----------------
// 32x32 PV A-slot k=8hi+i must match QK D-layout rows (r&3)+8(r>>2)+4hi:
// permutation = swap bits 2<->3 of the within-64 key index (involution).
__global__ void transpose_v(const bf16_t* __restrict__ KVb, bf16_t* __restrict__ Vt) {
  __shared__ bf16_t tile[32][33];
  int t0 = blockIdx.y * 32, d0 = blockIdx.x * 32;
  int tx = threadIdx.x, ty = threadIdx.y;
#pragma unroll
  for (int dy = 0; dy < 32; dy += 8)
    tile[ty + dy][tx] = KVb[(size_t)(t0 + ty + dy) * 1024 + 512 + d0 + tx];
  __syncthreads();
  int tt = t0 + tx;
  int j = (tt & ~12) | ((tt & 8) >> 1) | ((tt & 4) << 1);   // swap bits 2,3
#pragma unroll
  for (int dy = 0; dy < 32; dy += 8)
    Vt[(size_t)(d0 + ty + dy) * SEQ + j] = tile[tx][ty + dy];
}

// ---------------- GEMM: C[M][N] = A[M][K] * Bt[N][K]^T (+bias) ----------------
template <int BIAS>
__global__ __launch_bounds__(256, 2)
void gemm_bt(const bf16_t* __restrict__ A, const bf16_t* __restrict__ Bt,
             void* __restrict__ Cout, const float* __restrict__ bias,
             int M, int N, int K) {
  __shared__ __align__(16) bf16_t ldsA[128 * 64];
  __shared__ __align__(16) bf16_t ldsB[128 * 64];
  const int t = threadIdx.x;
  const int w = t >> 6, l = t & 63;
  const int lg = l >> 4, lr = l & 15;
  const int bm = blockIdx.y, bn = blockIdx.x;
  const int wr = (w >> 1) * 64, wc = (w & 1) * 64;

  f32x4 acc[4][4] = {};

  for (int k0 = 0; k0 < K; k0 += 64) {
    __syncthreads();
#pragma unroll
    for (int i = 0; i < 4; ++i) {
      int idx = i * 256 + t;          // 0..1023, 16B granules
      int row = idx >> 3;             // 8 chunks per 64-col row
      int ch  = (idx & 7) ^ (row & 7);
      gload_lds16(A  + (size_t)(bm * 128 + row) * K + k0 + ch * 8, &ldsA[idx * 8]);
      gload_lds16(Bt + (size_t)(bn * 128 + row) * K + k0 + ch * 8, &ldsB[idx * 8]);
    }
    __syncthreads();
#pragma unroll
    for (int kk = 0; kk < 2; ++kk) {
      bf16x8 af[4], bfr[4];
#pragma unroll
      for (int m = 0; m < 4; ++m) {
        int row = wr + m * 16 + lr;
        int ch = (kk * 4 + lg) ^ (row & 7);
        af[m] = *(const bf16x8*)&ldsA[row * 64 + ch * 8];
      }
#pragma unroll
      for (int n = 0; n < 4; ++n) {
        int row = wc + n * 16 + lr;
        int ch = (kk * 4 + lg) ^ (row & 7);
        bfr[n] = *(const bf16x8*)&ldsB[row * 64 + ch * 8];
      }
#pragma unroll
      for (int m = 0; m < 4; ++m)
#pragma unroll
        for (int n = 0; n < 4; ++n)
          acc[m][n] = __builtin_amdgcn_mfma_f32_16x16x32_bf16(af[m], bfr[n], acc[m][n], 0, 0, 0);
    }
  }

  // D layout: col = lane&15, row = (lane>>4)*4 + r  [measured m89]
  const int row0 = bm * 128 + wr + lg * 4;
  const int col0 = bn * 128 + wc + lr;
  if (BIAS) {
    float* C = (float*)Cout;
#pragma unroll
    for (int n = 0; n < 4; ++n) {
      int col = col0 + n * 16;
      float b = bias[col];
#pragma unroll
      for (int m = 0; m < 4; ++m)
#pragma unroll
        for (int r = 0; r < 4; ++r)
          C[(size_t)(row0 + m * 16 + r) * N + col] = acc[m][n][r] + b;
    }
  } else {
    bf16_t* C = (bf16_t*)Cout;
#pragma unroll
    for (int m = 0; m < 4; ++m)
#pragma unroll
      for (int n = 0; n < 4; ++n) {
        int col = col0 + n * 16;
#pragma unroll
        for (int r = 0; r < 4; ++r)
          C[(size_t)(row0 + m * 16 + r) * N + col] = f2b(acc[m][n][r]);
      }
  }
}

// ---------------- causal flash attention (32x32 MFMA) ----------------
// 4 waves / 256 thr; waves 0-1 -> q-tile b (rows 0-31/32-63), waves 2-3 ->
// q-tile 63-b. Each wave: 32 q-rows via v_mfma_f32_32x32x16_bf16 (2x FLOP
// per instr & per LDS byte vs 16x16). Swapped QK^T: lane holds one q-row
// (col=l&31) x 32 keys -> 31 fmax + 1 shfl row-max, 31 fadd + 1 shfl row-sum.
// Key-permuted V (bits 2<->3) keeps P register-local. Defer-max THR=8.
__global__ __launch_bounds__(256, 2)
void attn_fwd(const bf16_t* __restrict__ Qb, const bf16_t* __restrict__ KVb,
              const bf16_t* __restrict__ Vt, bf16_t* __restrict__ ctx) {
  __shared__ __align__(16) bf16_t kt[2][64 * 128];     // K tiles, XOR-swizzled
  __shared__ __align__(16) bf16_t vts[2][128 * 64];    // V^T tiles (key-permuted), swizzled

  const int t = threadIdx.x;
  const int w = t >> 6, l = t & 63;
  const int lq = l & 31, hi = l >> 5;
  const int h = blockIdx.y, g = h >> 2;
  const int b = blockIdx.x;
  const int qt = (w >> 1) ? 63 - b : b;     // this wave's q-tile
  const int qrow0 = qt * 64 + (w & 1) * 32; // wave's first q-row
  const int q = qrow0 + lq;                 // lane's q-row

  // Q fragments (B-operand: col = l&31 = q, k = 16ks + 8hi + i)
  bf16x8 qf[8];
#pragma unroll
  for (int ks = 0; ks < 8; ++ks)
    qf[ks] = *(const bf16x8*)&Qb[(size_t)q * DM + h * HD + ks * 16 + hi * 8];

  f32x16 acc[4] = {};                       // O: 4 d-tiles x 16 rows
  float m_run = -1e30f, l_run = 0.f;        // per-lane q-row stats

  const bf16_t* ksrc = KVb + g * 128;
  const bf16_t* vsrc = Vt + (size_t)(g * 128) * SEQ;
  auto stage = [&](int buf, int kvt) {
#pragma unroll
    for (int i = 0; i < 4; ++i) {           // K [64][128]: 16 chunks/row
      int idx = i * 256 + t;
      int row = idx >> 4;
      int ch = (idx & 15) ^ (row & 7);
      gload_lds16(ksrc + (size_t)(kvt * 64 + row) * 1024 + ch * 8, &kt[buf][idx * 8]);
    }
#pragma unroll
    for (int i = 0; i < 4; ++i) {           // V^T [128][64]: 8 chunks/row
      int idx = i * 256 + t;
      int row = idx >> 3;
      int ch = (idx & 7) ^ (row & 7);
      gload_lds16(vsrc + (size_t)row * SEQ + kvt * 64 + ch * 8, &vts[buf][idx * 8]);
    }
  };

  const int nkv = 64 - b;                   // heavy tile needs all of them
  stage(0, 0);

  for (int kv = 0; kv < nkv; ++kv) {
    const int cur = kv & 1;
    const int kv0 = kv * 64;
    __syncthreads();                        // kt/vts[cur] ready (vmcnt drained)
    if (kv + 1 < nkv) stage(cur ^ 1, kv + 1);

    if (kv <= qt) {                         // causal: tile active for this wave
      // S^T = K Q^T: lane holds q = lq, keys (r&3)+8(r>>2)+4hi per 32-key tile
      f32x16 s[2] = {};
      __builtin_amdgcn_s_setprio(1);
#pragma unroll
      for (int kti = 0; kti < 2; ++kti) {
        int row = kti * 32 + lq;
        int swz = row & 7;
#pragma unroll
        for (int ks = 0; ks < 8; ++ks) {
          int ch = (2 * ks + hi) ^ swz;
          bf16x8 kf = *(const bf16x8*)&kt[cur][row * 128 + ch * 8];
          s[kti] = __builtin_amdgcn_mfma_f32_32x32x16_bf16(kf, qf[ks], s[kti], 0, 0, 0);
        }
      }
      __builtin_amdgcn_s_setprio(0);

      if (kv == qt) {                       // diagonal tile: causal mask
#pragma unroll
        for (int kti = 0; kti < 2; ++kti)
#pragma unroll
          for (int r = 0; r < 16; ++r) {
            int key = kv0 + kti * 32 + (r & 3) + 8 * (r >> 2) + 4 * hi;
            if (key > q) s[kti][r] = -1e30f;
          }
      }

      // row max: 31 in-lane fmax + 1 shfl across lane halves
      float pm = s[0][0];
#pragma unroll
      for (int kti = 0; kti < 2; ++kti)
#pragma unroll
        for (int r = 0; r < 16; ++r)
          pm = fmaxf(pm, s[kti][r]);
      pm = fmaxf(pm, __shfl_xor(pm, 32, 64));

      if (__any((int)(pm > m_run + 8.f))) { // defer-max (T13)
        float mn = fmaxf(m_run, pm);
        float a_s = exp2f(m_run - mn);
        m_run = mn;
        l_run *= a_s;
        float alpha[16];
#pragma unroll
        for (int r = 0; r < 16; ++r)        // O rows (r&3)+8(r>>2)+4hi
          alpha[r] = __shfl(a_s, (r & 3) + 8 * (r >> 2) + 4 * hi, 64);
#pragma unroll
        for (int dt = 0; dt < 4; ++dt)
#pragma unroll
          for (int r = 0; r < 16; ++r)
            acc[dt][r] *= alpha[r];
      }

      // P = exp2(s - m): sum in-lane, pack to bf16 A-frags (reg-local)
      float rsum = 0.f;
      bf16x8 pf[4];
#pragma unroll
      for (int kti = 0; kti < 2; ++kti) {
        float p[16];
#pragma unroll
        for (int r = 0; r < 16; ++r) {
          p[r] = exp2f(s[kti][r] - m_run);
          rsum += p[r];
        }
        pf[2 * kti] = __builtin_bit_cast(bf16x8, (uint32x4){
            cvtpk(p[0], p[1]), cvtpk(p[2], p[3]), cvtpk(p[4], p[5]), cvtpk(p[6], p[7])});
        pf[2 * kti + 1] = __builtin_bit_cast(bf16x8, (uint32x4){
            cvtpk(p[8], p[9]), cvtpk(p[10], p[11]), cvtpk(p[12], p[13]), cvtpk(p[14], p[15])});
      }
      rsum += __shfl_xor(rsum, 32, 64);
      l_run += rsum;

      // O += P * V (4 K-steps x 4 d-tiles)
      __builtin_amdgcn_s_setprio(1);
#pragma unroll
      for (int sstep = 0; sstep < 4; ++sstep) {
#pragma unroll
        for (int dt = 0; dt < 4; ++dt) {
          int row = dt * 32 + lq;
          int ch = (2 * sstep + hi) ^ (row & 7);
          bf16x8 vf = *(const bf16x8*)&vts[cur][row * 64 + ch * 8];
          acc[dt] = __builtin_amdgcn_mfma_f32_32x32x16_bf16(pf[sstep], vf, acc[dt], 0, 0, 0);
        }
      }
      __builtin_amdgcn_s_setprio(0);
    }
  }

  // epilogue: rows (r&3)+8(r>>2)+4hi; l_run broadcast from the lane owning q
#pragma unroll
  for (int r = 0; r < 16; ++r) {
    int row = (r & 3) + 8 * (r >> 2) + 4 * hi;
    float ll = __shfl(l_run, row, 64);
    float rl = 1.0f / ll;
    int qrow = qrow0 + row;
#pragma unroll
    for (int dt = 0; dt < 4; ++dt)
      ctx[(size_t)qrow * DM + h * HD + dt * 32 + lq] = f2b(acc[dt][r] * rl);
  }
}

extern "C" void kernel_launch(void* const* d_in, const int* in_sizes, int n_in,
                              void* d_out, int out_size, void* d_ws, size_t ws_size,
                              hipStream_t stream) {
  const float* x  = (const float*)d_in[0];
  const float* Wq = (const float*)d_in[1];
  const float* Wk = (const float*)d_in[2];
  const float* Wv = (const float*)d_in[3];
  const float* Wo = (const float*)d_in[4];
  const float* bo = (const float*)d_in[5];
  float* out = (float*)d_out;

  char* p = (char*)d_ws;
  bf16_t* xb   = (bf16_t*)p;                          // also reused as ctx later
  bf16_t* ctx  = xb;                                  // xb dead after KV GEMM
  p += (size_t)SEQ * DM * 2;                          // 16.8 MB
  bf16_t* Wqt  = (bf16_t*)p; p += (size_t)DM * DM * 2;        // 8.4 MB
  bf16_t* Wkvt = (bf16_t*)p; p += (size_t)1024 * DM * 2;      // 4.2 MB
  bf16_t* Wot  = (bf16_t*)p; p += (size_t)DM * DM * 2;        // 8.4 MB
  bf16_t* Qb   = (bf16_t*)p; p += (size_t)SEQ * DM * 2;       // 16.8 MB
  bf16_t* KVb  = (bf16_t*)p; p += (size_t)SEQ * 1024 * 2;     // 8.4 MB
  bf16_t* Vt   = (bf16_t*)p; p += (size_t)512 * SEQ * 2;      // 4.2 MB
  float*  ctab = (float*)p;  p += (size_t)SEQ * 64 * 4;       // 1 MB
  float*  stab = (float*)p;  p += (size_t)SEQ * 64 * 4;       // 1 MB

  // 1. casts / transposes
  cast_x_bf16<<<(SEQ * DM / 4 + 255) / 256, 256, 0, stream>>>(x, xb, SEQ * DM / 4);
  transpose_cast_w<<<dim3(DM / 32, DM / 32), dim3(32, 8), 0, stream>>>(Wq, Wqt, DM, DM);
  transpose_cast_w<<<dim3(512 / 32, DM / 32), dim3(32, 8), 0, stream>>>(Wk, Wkvt, DM, 512);
  transpose_cast_w<<<dim3(512 / 32, DM / 32), dim3(32, 8), 0, stream>>>(Wv, Wkvt + (size_t)512 * DM, DM, 512);
  transpose_cast_w<<<dim3(DM / 32, DM / 32), dim3(32, 8), 0, stream>>>(Wo, Wot, DM, DM);
  rope_tab<<<(SEQ * 64 + 255) / 256, 256, 0, stream>>>(ctab, stab);

  // 2. projections
  gemm_bt<0><<<dim3(DM / 128, SEQ / 128), 256, 0, stream>>>(xb, Wqt, Qb, nullptr, SEQ, DM, DM);
  gemm_bt<0><<<dim3(1024 / 128, SEQ / 128), 256, 0, stream>>>(xb, Wkvt, KVb, nullptr, SEQ, 1024, DM);

  // 3. RoPE + V transpose (key-permuted layout, bits 2<->3)
  rope_apply<<<(SEQ * (NH + KVH) * 64 + 255) / 256, 256, 0, stream>>>(Qb, KVb, ctab, stab);
  transpose_v<<<dim3(512 / 32, SEQ / 32), dim3(32, 8), 0, stream>>>(KVb, Vt);

  // 4. attention (ctx aliases xb region — xb no longer needed)
  attn_fwd<<<dim3(32, NH), 256, 0, stream>>>(Qb, KVb, Vt, ctx);

  // 5. output projection + bias
  gemm_bt<1><<<dim3(DM / 128, SEQ / 128), 256, 0, stream>>>(ctx, Wot, out, bo, SEQ, DM, DM);
}

// Round 8
// 268.380 us; speedup vs baseline: 1.1529x; 1.1529x over previous
//
#include <hip/hip_runtime.h>
#include <cstdint>
#include <cstddef>

#define SEQ 4096
#define DM  2048
#define NH  16
#define KVH 4
#define HD  128
// softmax scale folded into Q at RoPE time: 1/sqrt(128) * log2(e)
#define QSCALE (0.08838834764831845f * 1.4426950408889634f)

typedef short bf16_t;
typedef __attribute__((ext_vector_type(8))) short bf16x8;
typedef __attribute__((ext_vector_type(4))) float f32x4;
typedef __attribute__((ext_vector_type(4))) unsigned uint32x4;

__device__ __forceinline__ bf16_t f2b(float f) {
  unsigned u = __builtin_bit_cast(unsigned, f);
  u += 0x7fffu + ((u >> 16) & 1u);          // RNE
  return (bf16_t)(u >> 16);
}
__device__ __forceinline__ float b2f(bf16_t s) {
  unsigned u = ((unsigned)(unsigned short)s) << 16;
  return __builtin_bit_cast(float, u);
}
// v_cvt_pk_bf16_f32: packs 2 f32 -> 2 bf16 (RNE) in one instr (no builtin; T12)
__device__ __forceinline__ unsigned cvtpk(float lo, float hi) {
  unsigned r;
  asm("v_cvt_pk_bf16_f32 %0, %1, %2" : "=v"(r) : "v"(lo), "v"(hi));
  return r;
}

// async global->LDS, 16B per lane. LDS dest is wave-uniform base + lane*16
// (linear); swizzling is done by permuting the per-lane GLOBAL source.
__device__ __forceinline__ void gload_lds16(const void* gsrc, void* ldst) {
  __builtin_amdgcn_global_load_lds(
      (__attribute__((address_space(1))) void*)gsrc,
      (__attribute__((address_space(3))) void*)ldst, 16, 0, 0);
}

// ---------------- cast x -> bf16 ----------------
__global__ void cast_x_bf16(const float* __restrict__ x, bf16_t* __restrict__ xb, int n4) {
  int i = blockIdx.x * 256 + threadIdx.x;
  if (i >= n4) return;
  float4 v = ((const float4*)x)[i];
  union { bf16_t h[4]; unsigned long long u; } o;
  o.h[0] = f2b(v.x); o.h[1] = f2b(v.y); o.h[2] = f2b(v.z); o.h[3] = f2b(v.w);
  ((unsigned long long*)xb)[i] = o.u;
}

// ---------------- W [K][N] fp32 -> Wt [N][K] bf16 ----------------
__global__ void transpose_cast_w(const float* __restrict__ W, bf16_t* __restrict__ Wt,
                                 int K, int N) {
  __shared__ float tile[32][33];
  int k0 = blockIdx.y * 32, n0 = blockIdx.x * 32;
  int tx = threadIdx.x, ty = threadIdx.y;
#pragma unroll
  for (int dy = 0; dy < 32; dy += 8)
    tile[ty + dy][tx] = W[(size_t)(k0 + ty + dy) * N + n0 + tx];
  __syncthreads();
#pragma unroll
  for (int dy = 0; dy < 32; dy += 8)
    Wt[(size_t)(n0 + ty + dy) * K + k0 + tx] = f2b(tile[tx][ty + dy]);
}

// ---------------- RoPE cos/sin table ----------------
__global__ void rope_tab(float* __restrict__ ct, float* __restrict__ st) {
  int i = blockIdx.x * 256 + threadIdx.x;
  if (i >= SEQ * 64) return;
  int t = i >> 6, j = i & 63;
  float invf = expf(-(float)j * (9.210340371976184f / 64.0f)); // 10000^(-j/64)
  float ang = (float)t * invf;
  ct[i] = cosf(ang);
  st[i] = sinf(ang);
}

// ---------------- in-place RoPE on bf16 Q and K (Q pre-scaled) ----------------
__global__ void rope_apply(bf16_t* __restrict__ Qb, bf16_t* __restrict__ KVb,
                           const float* __restrict__ ct, const float* __restrict__ st) {
  int i = blockIdx.x * 256 + threadIdx.x;
  const int qtot = SEQ * NH * 64;
  const int tot = qtot + SEQ * KVH * 64;
  if (i >= tot) return;
  bf16_t* base; int t, j; float scl;
  if (i < qtot) {
    t = i >> 10; int rem = i & 1023; int hh = rem >> 6; j = rem & 63;
    base = Qb + (size_t)t * DM + hh * HD;
    scl = QSCALE;                              // fold softmax scale + log2e into Q
  } else {
    int i2 = i - qtot;
    t = i2 >> 8; int rem = i2 & 255; int hh = rem >> 6; j = rem & 63;
    base = KVb + (size_t)t * 1024 + hh * HD;   // K half = cols 0..511
    scl = 1.0f;
  }
  float c = ct[t * 64 + j], s = st[t * 64 + j];
  float x0 = b2f(base[j]);
  float x1 = b2f(base[j + 64]);
  base[j]      = f2b((x0 * c - x1 * s) * scl);
  base[j + 64] = f2b((x1 * c + x0 * s) * scl);
}

// ---------------- V half of KVb [T][1024] -> Vt [512][T], key-permuted ----------------
// Column index carries pi^-1 within each 64-key block:
//   pi(32a+8lg+4h+r) = 32a+16h+4lg+r  (PV A-slot -> true key, 16x16 pipeline)
// so P fragments after swapped-QK^T stay lane-local (pure register pack).
__global__ void transpose_v(const bf16_t* __restrict__ KVb, bf16_t* __restrict__ Vt) {
  __shared__ bf16_t tile[32][33];
  int t0 = blockIdx.y * 32, d0 = blockIdx.x * 32;
  int tx = threadIdx.x, ty = threadIdx.y;
#pragma unroll
  for (int dy = 0; dy < 32; dy += 8)
    tile[ty + dy][tx] = KVb[(size_t)(t0 + ty + dy) * 1024 + 512 + d0 + tx];
  __syncthreads();
  int tt = t0 + tx;
  int j = (tt & ~63) | (tt & 32) | ((tt & 12) << 1) | ((tt & 16) >> 2) | (tt & 3);
#pragma unroll
  for (int dy = 0; dy < 32; dy += 8)
    Vt[(size_t)(d0 + ty + dy) * SEQ + j] = tile[tx][ty + dy];
}

// ---------------- shared GEMM core: 128x128 tile, BK=64, 4 waves ----------------
// MODE 0: bf16 out, split at col 2048 -> C0 (stride 2048) / C1 (stride 1024)
// MODE 1: fp32 out + bias, single C0 (stride N)
template <int MODE>
__global__ __launch_bounds__(256, MODE == 0 ? 3 : 2)
void gemm_bt(const bf16_t* __restrict__ A, const bf16_t* __restrict__ Bt,
             void* __restrict__ C0out, void* __restrict__ C1out,
             const float* __restrict__ bias, int M, int N, int K) {
  __shared__ __align__(16) bf16_t ldsA[128 * 64];
  __shared__ __align__(16) bf16_t ldsB[128 * 64];
  const int t = threadIdx.x;
  const int w = t >> 6, l = t & 63;
  const int lg = l >> 4, lr = l & 15;
  const int bm = blockIdx.y, bn = blockIdx.x;
  const int wr = (w >> 1) * 64, wc = (w & 1) * 64;

  f32x4 acc[4][4] = {};

  for (int k0 = 0; k0 < K; k0 += 64) {
    __syncthreads();
#pragma unroll
    for (int i = 0; i < 4; ++i) {
      int idx = i * 256 + t;          // 0..1023, 16B granules
      int row = idx >> 3;             // 8 chunks per 64-col row
      int ch  = (idx & 7) ^ (row & 7);
      gload_lds16(A  + (size_t)(bm * 128 + row) * K + k0 + ch * 8, &ldsA[idx * 8]);
      gload_lds16(Bt + (size_t)(bn * 128 + row) * K + k0 + ch * 8, &ldsB[idx * 8]);
    }
    __syncthreads();
#pragma unroll
    for (int kk = 0; kk < 2; ++kk) {
      bf16x8 af[4], bfr[4];
#pragma unroll
      for (int m = 0; m < 4; ++m) {
        int row = wr + m * 16 + lr;
        int ch = (kk * 4 + lg) ^ (row & 7);
        af[m] = *(const bf16x8*)&ldsA[row * 64 + ch * 8];
      }
#pragma unroll
      for (int n = 0; n < 4; ++n) {
        int row = wc + n * 16 + lr;
        int ch = (kk * 4 + lg) ^ (row & 7);
        bfr[n] = *(const bf16x8*)&ldsB[row * 64 + ch * 8];
      }
#pragma unroll
      for (int m = 0; m < 4; ++m)
#pragma unroll
        for (int n = 0; n < 4; ++n)
          acc[m][n] = __builtin_amdgcn_mfma_f32_16x16x32_bf16(af[m], bfr[n], acc[m][n], 0, 0, 0);
    }
  }

  // D layout: col = lane&15, row = (lane>>4)*4 + r  [measured m89]
  const int row0 = bm * 128 + wr + lg * 4;
  if (MODE == 1) {
    float* C = (float*)C0out;
    const int col0 = bn * 128 + wc + lr;
#pragma unroll
    for (int n = 0; n < 4; ++n) {
      int col = col0 + n * 16;
      float b = bias[col];
#pragma unroll
      for (int m = 0; m < 4; ++m)
#pragma unroll
        for (int r = 0; r < 4; ++r)
          C[(size_t)(row0 + m * 16 + r) * N + col] = acc[m][n][r] + b;
    }
  } else {
    // QKV split: colbase is 64-aligned, regions 2048-aligned -> uniform branch
    const int colbase = bn * 128 + wc;
    bf16_t* C; int stride, cb;
    if (colbase < 2048) { C = (bf16_t*)C0out; stride = 2048; cb = colbase; }
    else                { C = (bf16_t*)C1out; stride = 1024; cb = colbase - 2048; }
#pragma unroll
    for (int m = 0; m < 4; ++m)
#pragma unroll
      for (int n = 0; n < 4; ++n) {
        int col = cb + n * 16 + lr;
#pragma unroll
        for (int r = 0; r < 4; ++r)
          C[(size_t)(row0 + m * 16 + r) * stride + col] = f2b(acc[m][n][r]);
      }
  }
}

// ---------------- causal flash attention (R6 structure, verified 135 us) ----------------
// 8 waves / 512 threads per block; paired q-tiles (b, 63-b): waves 0-3 own
// q-tile b (16 rows each), waves 4-7 own q-tile 63-b -> 4 waves/SIMD at
// 2 blocks/CU. Swapped QK^T, key-permuted V (P in registers), ones-column
// row-sum, defer-max (THR=8), K+V double-buffered LDS, one barrier per tile.
__global__ __launch_bounds__(512, 4)
void attn_fwd(const bf16_t* __restrict__ Qb, const bf16_t* __restrict__ KVb,
              const bf16_t* __restrict__ Vt, bf16_t* __restrict__ ctx) {
  __shared__ __align__(16) bf16_t kt[2][64 * 128];     // K tiles, XOR-swizzled
  __shared__ __align__(16) bf16_t vts[2][128 * 64];    // V^T tiles (key-permuted), swizzled

  const int t = threadIdx.x;
  const int w = t >> 6, l = t & 63;
  const int lg = l >> 4, lr = l & 15;
  const int h = blockIdx.y, g = h >> 2;
  const int b = blockIdx.x;
  const int m = w >> 2, wq = w & 3;
  const int qt = m ? 63 - b : b;            // this wave's q-tile
  const int qrow0 = qt * 64 + wq * 16;      // wave's first q-row

  // Q fragments (B-operand after swap; row/col = lane&15, k = (lane>>4)*8+i)
  bf16x8 qf[4];
#pragma unroll
  for (int kk = 0; kk < 4; ++kk)
    qf[kk] = *(const bf16x8*)&Qb[(size_t)(qrow0 + lr) * DM + h * HD + kk * 32 + lg * 8];

  f32x4 acc[9] = {};                        // [8] = row-sum (ones column)
  float m_run = -1e30f;                     // per-lane q-row = lr (scaled units)

  bf16x8 ones;
#pragma unroll
  for (int i = 0; i < 8; ++i) ones[i] = (short)0x3F80;  // bf16 1.0

  const bf16_t* ksrc = KVb + g * 128;
  const bf16_t* vsrc = Vt + (size_t)(g * 128) * SEQ;
  auto stage = [&](int buf, int kvt) {
#pragma unroll
    for (int i = 0; i < 2; ++i) {           // K [64][128]: 1024 granules, 16/row
      int idx = i * 512 + t;
      int row = idx >> 4;
      int ch = (idx & 15) ^ (row & 7);
      gload_lds16(ksrc + (size_t)(kvt * 64 + row) * 1024 + ch * 8, &kt[buf][idx * 8]);
    }
#pragma unroll
    for (int i = 0; i < 2; ++i) {           // V^T [128][64]: 1024 granules, 8/row
      int idx = i * 512 + t;
      int row = idx >> 3;
      int ch = (idx & 7) ^ (row & 7);
      gload_lds16(vsrc + (size_t)row * SEQ + kvt * 64 + ch * 8, &vts[buf][idx * 8]);
    }
  };

  const int nkv = 64 - b;                   // qt1 + 1
  stage(0, 0);

  for (int kv = 0; kv < nkv; ++kv) {
    const int cur = kv & 1;
    const int kv0 = kv * 64;
    __syncthreads();                        // kt/vts[cur] ready (vmcnt drained)
    if (kv + 1 < nkv) stage(cur ^ 1, kv + 1);

    if (kv <= qt) {                         // causal: tile active for this wave
      // S^T = K Q^T (swapped): lane holds q = lr, key = kv0 + n*16 + lg*4 + r
      f32x4 s[4] = {};
      __builtin_amdgcn_s_setprio(1);
#pragma unroll
      for (int n = 0; n < 4; ++n) {
        int row = n * 16 + lr;
#pragma unroll
        for (int kk = 0; kk < 4; ++kk) {
          int ch = (kk * 4 + lg) ^ (row & 7);
          bf16x8 kf = *(const bf16x8*)&kt[cur][row * 128 + ch * 8];
          s[n] = __builtin_amdgcn_mfma_f32_16x16x32_bf16(kf, qf[kk], s[n], 0, 0, 0);
        }
      }
      __builtin_amdgcn_s_setprio(0);

      const int qrow = qrow0 + lr;
      if (kv == qt) {                       // diagonal tile: causal mask
#pragma unroll
        for (int n = 0; n < 4; ++n)
#pragma unroll
          for (int r = 0; r < 4; ++r) {
            int key = kv0 + n * 16 + lg * 4 + r;
            if (key > qrow) s[n][r] = -1e30f;
          }
      }

      // row max: in-lane over 16, then across the 4 lg lanes (xor 16, 32)
      float pm = s[0][0];
#pragma unroll
      for (int n = 0; n < 4; ++n)
#pragma unroll
        for (int r = 0; r < 4; ++r)
          pm = fmaxf(pm, s[n][r]);
      pm = fmaxf(pm, __shfl_xor(pm, 16, 64));
      pm = fmaxf(pm, __shfl_xor(pm, 32, 64));

      if (__any((int)(pm > m_run + 8.f))) { // defer-max (T13)
        float mn = fmaxf(m_run, pm);
        float a_s = exp2f(m_run - mn);
        m_run = mn;
        float alpha[4];
#pragma unroll
        for (int r = 0; r < 4; ++r)         // broadcast to O-domain rows lg*4+r
          alpha[r] = __shfl(a_s, (l & 48) | (lg * 4 + r), 64);
#pragma unroll
        for (int nd = 0; nd < 9; ++nd)
#pragma unroll
          for (int r = 0; r < 4; ++r)
            acc[nd][r] *= alpha[r];
      }

      // P = exp2(s - m), packed to bf16 in registers (key-permuted V layout)
      unsigned u[8];
#pragma unroll
      for (int n = 0; n < 4; ++n) {
        u[2 * n]     = cvtpk(exp2f(s[n][0] - m_run), exp2f(s[n][1] - m_run));
        u[2 * n + 1] = cvtpk(exp2f(s[n][2] - m_run), exp2f(s[n][3] - m_run));
      }
      bf16x8 pf[2];
      pf[0] = __builtin_bit_cast(bf16x8, (uint32x4){u[0], u[1], u[2], u[3]});
      pf[1] = __builtin_bit_cast(bf16x8, (uint32x4){u[4], u[5], u[6], u[7]});

      // O += P * V; row-sum via ones column
      __builtin_amdgcn_s_setprio(1);
#pragma unroll
      for (int kk2 = 0; kk2 < 2; ++kk2) {
#pragma unroll
        for (int nd = 0; nd < 8; ++nd) {
          int vrow = nd * 16 + lr;
          int vch = (kk2 * 4 + lg) ^ (lr & 7);
          bf16x8 vf = *(const bf16x8*)&vts[cur][vrow * 64 + vch * 8];
          acc[nd] = __builtin_amdgcn_mfma_f32_16x16x32_bf16(pf[kk2], vf, acc[nd], 0, 0, 0);
        }
        acc[8] = __builtin_amdgcn_mfma_f32_16x16x32_bf16(pf[kk2], ones, acc[8], 0, 0, 0);
      }
      __builtin_amdgcn_s_setprio(0);
    }
  }

#pragma unroll
  for (int r = 0; r < 4; ++r) {
    float rl = 1.0f / acc[8][r];
    int qrow = qrow0 + lg * 4 + r;
#pragma unroll
    for (int nd = 0; nd < 8; ++nd) {
      int col = h * HD + nd * 16 + lr;
      ctx[(size_t)qrow * DM + col] = f2b(acc[nd][r] * rl);
    }
  }
}

extern "C" void kernel_launch(void* const* d_in, const int* in_sizes, int n_in,
                              void* d_out, int out_size, void* d_ws, size_t ws_size,
                              hipStream_t stream) {
  const float* x  = (const float*)d_in[0];
  const float* Wq = (const float*)d_in[1];
  const float* Wk = (const float*)d_in[2];
  const float* Wv = (const float*)d_in[3];
  const float* Wo = (const float*)d_in[4];
  const float* bo = (const float*)d_in[5];
  float* out = (float*)d_out;

  char* p = (char*)d_ws;
  bf16_t* xb    = (bf16_t*)p;                         // also reused as ctx later
  bf16_t* ctx   = xb;                                 // xb dead after QKV GEMM
  p += (size_t)SEQ * DM * 2;                          // 16.8 MB
  bf16_t* Wqkvt = (bf16_t*)p; p += (size_t)3072 * DM * 2;     // 12.6 MB (Wq^T ++ Wk^T ++ Wv^T)
  bf16_t* Wot   = (bf16_t*)p; p += (size_t)DM * DM * 2;       // 8.4 MB
  bf16_t* Qb    = (bf16_t*)p; p += (size_t)SEQ * DM * 2;      // 16.8 MB
  bf16_t* KVb   = (bf16_t*)p; p += (size_t)SEQ * 1024 * 2;    // 8.4 MB
  bf16_t* Vt    = (bf16_t*)p; p += (size_t)512 * SEQ * 2;     // 4.2 MB
  float*  ctab  = (float*)p;  p += (size_t)SEQ * 64 * 4;      // 1 MB
  float*  stab  = (float*)p;  p += (size_t)SEQ * 64 * 4;      // 1 MB

  // 1. casts / transposes (Wq->rows 0..2047, Wk->2048..2559, Wv->2560..3071)
  cast_x_bf16<<<(SEQ * DM / 4 + 255) / 256, 256, 0, stream>>>(x, xb, SEQ * DM / 4);
  transpose_cast_w<<<dim3(DM / 32, DM / 32), dim3(32, 8), 0, stream>>>(Wq, Wqkvt, DM, DM);
  transpose_cast_w<<<dim3(512 / 32, DM / 32), dim3(32, 8), 0, stream>>>(Wk, Wqkvt + (size_t)2048 * DM, DM, 512);
  transpose_cast_w<<<dim3(512 / 32, DM / 32), dim3(32, 8), 0, stream>>>(Wv, Wqkvt + (size_t)2560 * DM, DM, 512);
  transpose_cast_w<<<dim3(DM / 32, DM / 32), dim3(32, 8), 0, stream>>>(Wo, Wot, DM, DM);
  rope_tab<<<(SEQ * 64 + 255) / 256, 256, 0, stream>>>(ctab, stab);

  // 2. fused QKV projection: N=3072, split outputs (768 blocks = 3/CU)
  gemm_bt<0><<<dim3(3072 / 128, SEQ / 128), 256, 0, stream>>>(
      xb, Wqkvt, Qb, KVb, nullptr, SEQ, 3072, DM);

  // 3. RoPE + V transpose (key-permuted layout)
  rope_apply<<<(SEQ * (NH + KVH) * 64 + 255) / 256, 256, 0, stream>>>(Qb, KVb, ctab, stab);
  transpose_v<<<dim3(512 / 32, SEQ / 32), dim3(32, 8), 0, stream>>>(KVb, Vt);

  // 4. attention (ctx aliases xb region — xb no longer needed)
  attn_fwd<<<dim3(32, NH), 512, 0, stream>>>(Qb, KVb, Vt, ctx);

  // 5. output projection + bias
  gemm_bt<1><<<dim3(DM / 128, SEQ / 128), 256, 0, stream>>>(
      ctx, Wot, out, nullptr, bo, SEQ, DM, DM);
}